// Round 6
// baseline (400.437 us; speedup 1.0000x reference)
//
#include <hip/hip_runtime.h>

typedef short bf16x8 __attribute__((ext_vector_type(8)));
typedef float f32x4 __attribute__((ext_vector_type(4)));
typedef float f32x16 __attribute__((ext_vector_type(16)));

__device__ __forceinline__ ushort f2bf(float f) {
    union { float f; unsigned u; } v; v.f = f;
    unsigned r = (v.u + 0x7fffu + ((v.u >> 16) & 1u)) >> 16;
    return (ushort)r;
}
__device__ __forceinline__ float bf2f(ushort u) {
    union { unsigned u; float f; } v; v.u = ((unsigned)u) << 16;
    return v.f;
}
__device__ __forceinline__ void async_copy16(void* lds, const void* g) {
    __builtin_amdgcn_global_load_lds(
        (const __attribute__((address_space(1))) unsigned*)g,
        (__attribute__((address_space(3))) unsigned*)lds, 16, 0, 0);
}
// Barrier that waits only LDS ops — leaves global loads in flight.
__device__ __forceinline__ void lds_barrier() {
    asm volatile("s_waitcnt lgkmcnt(0)\n\ts_barrier" ::: "memory");
}

// ---------------- fused prep: cvt_x | cvt_wT(Wq,Wk) | cvt(Wv) | compact ------
__global__ __launch_bounds__(256)
void prep_kernel(const float* __restrict__ x, const float* __restrict__ Wq,
                 const float* __restrict__ Wk, const float* __restrict__ Wv,
                 const int* __restrict__ mask,
                 ushort* __restrict__ xb, ushort* __restrict__ wqT,
                 ushort* __restrict__ wkT, ushort* __restrict__ wvb,
                 int* __restrict__ idx, int* __restrict__ cnt)
{
    const int bid = blockIdx.x, t = threadIdx.x;
    if (bid < 8192) {                       // x fp32 -> bf16
        int i = (bid * 256 + t) * 4;
        float4 v = *(const float4*)(x + i);
        ushort4 o;
        o.x = f2bf(v.x); o.y = f2bf(v.y); o.z = f2bf(v.z); o.w = f2bf(v.w);
        *(ushort4*)(xb + i) = o;
    } else if (bid < 8320) {                // Wq/Wk transpose-convert
        __shared__ ushort T[64][72];
        int r = bid - 8192;
        const int z = r >> 6; r &= 63;
        const float* in = z ? Wk : Wq;
        ushort* out     = z ? wkT : wqT;
        const int r0 = (r >> 3) * 64, c0 = (r & 7) * 64;
        const int rr = t >> 3, cc8 = (t & 7) * 8;
        #pragma unroll
        for (int pass = 0; pass < 2; ++pass) {
            int rw = rr + pass * 32;
            float4 a = *(const float4*)(in + (size_t)(r0 + rw) * 512 + c0 + cc8);
            float4 bq = *(const float4*)(in + (size_t)(r0 + rw) * 512 + c0 + cc8 + 4);
            T[rw][cc8+0]=f2bf(a.x);  T[rw][cc8+1]=f2bf(a.y);  T[rw][cc8+2]=f2bf(a.z);  T[rw][cc8+3]=f2bf(a.w);
            T[rw][cc8+4]=f2bf(bq.x); T[rw][cc8+5]=f2bf(bq.y); T[rw][cc8+6]=f2bf(bq.z); T[rw][cc8+7]=f2bf(bq.w);
        }
        __syncthreads();
        const int c = t >> 2, seg = (t & 3) * 16;
        ushort tmp[16];
        #pragma unroll
        for (int j = 0; j < 16; ++j) tmp[j] = T[seg + j][c];
        *(uint4*)(out + (size_t)(c0 + c) * 512 + r0 + seg)     = *(uint4*)&tmp[0];
        *(uint4*)(out + (size_t)(c0 + c) * 512 + r0 + seg + 8) = *(uint4*)&tmp[8];
    } else if (bid < 8576) {                // Wv fp32 -> bf16
        int i = ((bid - 8320) * 256 + t) * 4;
        float4 v = *(const float4*)(Wv + i);
        ushort4 o;
        o.x = f2bf(v.x); o.y = f2bf(v.y); o.z = f2bf(v.z); o.w = f2bf(v.w);
        *(ushort4*)(wvb + i) = o;
    } else {                                // mask compaction
        __shared__ int sc[256];
        int seg = bid - 8576, b = seg >> 1, half = seg & 1;
        const int* m = mask + b * 2048 + half * 1024;
        int v0 = (m[t*4+0] == 0), v1 = (m[t*4+1] == 0);
        int v2 = (m[t*4+2] == 0), v3 = (m[t*4+3] == 0);
        int c = v0 + v1 + v2 + v3;
        sc[t] = c; __syncthreads();
        for (int ofs = 1; ofs < 256; ofs <<= 1) {
            int xx = (t >= ofs) ? sc[t - ofs] : 0;
            __syncthreads(); sc[t] += xx; __syncthreads();
        }
        int pos = sc[t] - c + seg * 1024;
        if (v0) idx[pos++] = t*4+0;
        if (v1) idx[pos++] = t*4+1;
        if (v2) idx[pos++] = t*4+2;
        if (v3) idx[pos++] = t*4+3;
        if (t == 255) cnt[seg] = sc[255];
    }
}

// ------- gather unmasked rows from bf16 xb (already converted), zero-pad -----
__global__ __launch_bounds__(256)
void gather_cvt(const ushort* __restrict__ xb, const int* __restrict__ idx,
                const int* __restrict__ cnt, ushort* __restrict__ xc)
{
    int seg = blockIdx.x, b = seg >> 1, half = seg & 1;
    int n = cnt[seg];
    int wave = threadIdx.x >> 6, lane = threadIdx.x & 63;
    int j0 = blockIdx.y * 64 + wave * 16;
    for (int i = 0; i < 16; ++i) {
        int j = j0 + i;
        uint4 val = {0u, 0u, 0u, 0u};
        if (j < n) {
            int src = idx[seg * 1024 + j];
            val = *(const uint4*)(xb + ((size_t)(b * 2048 + half * 1024 + src)) * 512 + lane * 8);
        }
        *(uint4*)(xc + ((size_t)(seg * 1024 + j)) * 512 + lane * 8) = val;
    }
}

// ---------------- shared GEMM core: C[m][n] = sum_k A[m][k]*B[n][k] ----------
// mode 0: linear C[m*N+n].
// mode 1: V-fragment-tiled [seg][kt32][db16][g2][dr32][k16]
//   (seg=n>>10, key=n&1023 -> kt32=key>>5, g2=(key>>4)&1, k=key&15;
//    db=m>>5, dr=m&31).
// mode 2: K-fragment-tiled [seg][kt64][frag(g*16+ks)][lq4][lr16][j8]
//   (seg=m>>10, key=m&1023 -> kt64=key>>6, g=(key>>4)&3, lr=key&15;
//    n -> ks=n>>5, lq=(n&31)>>3, j=n&7).
__device__ __forceinline__ void gemm_core(const ushort* __restrict__ A,
                                          const ushort* __restrict__ B,
                                          ushort* __restrict__ C,
                                          int N, int K, int mBase, int nBase,
                                          int mode)
{
    __shared__ ushort As[128][32];
    __shared__ ushort Bs[128][32];
    const int tid = threadIdx.x;
    const int lane = tid & 63, wave = tid >> 6;
    const int wm = wave >> 1, wn = wave & 1;
    const int lr = lane & 15, lq = lane >> 4;
    const int sr = lane >> 2;
    const int sc = (lane & 3) * 8;

    f32x4 acc[4][4];
    #pragma unroll
    for (int i = 0; i < 4; ++i)
        #pragma unroll
        for (int j = 0; j < 4; ++j) acc[i][j] = (f32x4){0.f, 0.f, 0.f, 0.f};

    for (int k0 = 0; k0 < K; k0 += 32) {
        __syncthreads();
        #pragma unroll
        for (int j = 0; j < 2; ++j) {
            int rbase = wave * 32 + j * 16;
            async_copy16(&As[rbase][0], A + (size_t)(mBase + rbase + sr) * K + k0 + sc);
            async_copy16(&Bs[rbase][0], B + (size_t)(nBase + rbase + sr) * K + k0 + sc);
        }
        __syncthreads();
        bf16x8 af[4], bfr[4];
        #pragma unroll
        for (int mi = 0; mi < 4; ++mi) af[mi] = *(const bf16x8*)&As[wm * 64 + mi * 16 + lr][lq * 8];
        #pragma unroll
        for (int ni = 0; ni < 4; ++ni) bfr[ni] = *(const bf16x8*)&Bs[wn * 64 + ni * 16 + lr][lq * 8];
        #pragma unroll
        for (int mi = 0; mi < 4; ++mi)
            #pragma unroll
            for (int ni = 0; ni < 4; ++ni)
                acc[mi][ni] = __builtin_amdgcn_mfma_f32_16x16x32_bf16(af[mi], bfr[ni], acc[mi][ni], 0, 0, 0);
    }
    #pragma unroll
    for (int mi = 0; mi < 4; ++mi)
        #pragma unroll
        for (int ni = 0; ni < 4; ++ni)
            #pragma unroll
            for (int r = 0; r < 4; ++r) {
                int m = mBase + wm * 64 + mi * 16 + lq * 4 + r;
                int n = nBase + wn * 64 + ni * 16 + lr;
                float val = acc[mi][ni][r];
                if (mode == 0) {
                    C[(size_t)m * N + n] = f2bf(val);
                } else if (mode == 1) {
                    int sseg = n >> 10, key = n & 1023;
                    size_t ix = (size_t)sseg * 524288 + (size_t)(key >> 5) * 16384
                              + (size_t)(m >> 5) * 1024 + ((key >> 4) & 1) * 512
                              + (m & 31) * 16 + (key & 15);
                    C[ix] = f2bf(val);
                } else {
                    int sseg = m >> 10, key = m & 1023;
                    size_t ix = (size_t)sseg * 524288 + (size_t)(key >> 6) * 32768
                              + (size_t)((((key >> 4) & 3) * 16) + (n >> 5)) * 512
                              + ((n & 31) >> 3) * 128 + (key & 15) * 8 + (n & 7);
                    C[ix] = f2bf(val);
                }
            }
}

__global__ __launch_bounds__(256, 2)
void gemm_m(const ushort* __restrict__ A, const ushort* __restrict__ B,
            ushort* __restrict__ C) {
    gemm_core(A, B, C, 512, 512, blockIdx.y * 128, blockIdx.x * 128, 0);
}

// fused K' and Vt gemms (z-decode); both skip all-pad 128-bands
__global__ __launch_bounds__(256, 2)
void gemm_kv(const ushort* __restrict__ xc, const ushort* __restrict__ Mb,
             ushort* __restrict__ Kc, const ushort* __restrict__ wv,
             ushort* __restrict__ Vtc, const int* __restrict__ cnt)
{
    if (blockIdx.z == 0) {
        int mBase = blockIdx.y * 128, nBase = blockIdx.x * 128;
        if ((mBase & 1023) >= cnt[mBase >> 10]) return;
        gemm_core(xc, Mb, Kc, 512, 512, mBase, nBase, 2);
    } else {
        int mBase = blockIdx.x * 128, nBase = blockIdx.y * 128;
        if ((nBase & 1023) >= cnt[nBase >> 10]) return;
        gemm_core(wv, xc, Vtc, 16384, 512, mBase, nBase, 1);
    }
}

// ---------------- flash attention over COMPACTED keys (R8-exact) -------------
// Q = xb [B*S][512] bf16 (registers). K' frag-tiled: [16][kt64][32 frags][1KB].
// Vt frag-tiled: [16][kt32][db16][g2][dr32][k16]. Both read DIRECTLY from
// L2-resident global (XCD swizzle pins each seg's 2x1MB to one XCD's L2) —
// no K/V LDS staging at all. LDS = P round-trip only (17 KB), ONE lgkm-only
// barrier per 64-key iteration, no vmcnt drains. This attacks the measured
// bottleneck: R3 was LDS-pipe-throughput-bound (~512 DS insts/CU/iter);
// R4 proved Ks scheme conflict-free and Vs caused all bank conflicts.
__global__ __launch_bounds__(256, 2)
void attn_kernel(const ushort* __restrict__ Qg, const ushort* __restrict__ Kcg,
                 const ushort* __restrict__ Vtcg, const int* __restrict__ cntg,
                 ushort* __restrict__ Pog, float* __restrict__ Mlg)
{
    const int S = 2048;
    const float SL2E = 0.0637587160f;  // (1/sqrt(512)) * log2(e)

    __shared__ ushort Ps[2][2][32][68];   // [kt parity][q-half p][row][key]

    // XCD swizzle: all 32 q-tiles of a segment on one XCD (2 segs/XCD).
    const int lin = blockIdx.x + 32 * blockIdx.y + 256 * blockIdx.z;
    const int seg = (lin & 7) * 2 + (lin >> 8);
    const int qt  = (lin >> 3) & 31;
    const int b = seg >> 1, half = seg & 1;

    const int tid = threadIdx.x, lane = tid & 63, wave = tid >> 6;
    const int lr = lane & 15, lq = lane >> 4;
    const int p = wave >> 1, s = wave & 1;
    const int l32 = lane & 31, lh = lane >> 5;

    const int n = cntg[seg];
    const int ntiles = (n + 63) >> 6;   // 64-key tiles

    const ushort* Qp = Qg + ((size_t)b * S + qt * 64 + wave * 16 + lr) * 512;
    bf16x8 qf[16];
    #pragma unroll
    for (int c = 0; c < 16; ++c) qf[c] = *(const bf16x8*)(Qp + c * 32 + lq * 8);

    f32x16 o[8];
    #pragma unroll
    for (int i = 0; i < 8; ++i)
        #pragma unroll
        for (int r = 0; r < 16; ++r) o[i][r] = 0.f;
    float l_i[4] = {0.f, 0.f, 0.f, 0.f};

    const ushort* Kseg = Kcg + (size_t)seg * 524288;
    const ushort* Vseg = Vtcg + (size_t)seg * 524288;

    for (int kt = 0; kt < ntiles; ++kt) {
        const int key0 = kt * 64;
        const int par = kt & 1;
        // ---- QK^T: fragments streamed from L2 (frag-tiled K'). ----
        const ushort* Kt = Kseg + (size_t)kt * 32768 + lane * 8;
        f32x4 sf[4][2];
        #pragma unroll
        for (int g = 0; g < 4; ++g) {
            sf[g][0] = (f32x4){0.f,0.f,0.f,0.f};
            sf[g][1] = (f32x4){0.f,0.f,0.f,0.f};
        }
        __builtin_amdgcn_s_setprio(1);
        #pragma unroll
        for (int ks = 0; ks < 16; ++ks) {
            #pragma unroll
            for (int g = 0; g < 4; ++g) {
                bf16x8 kf = *(const bf16x8*)(Kt + (g * 16 + ks) * 512);
                sf[g][ks & 1] = __builtin_amdgcn_mfma_f32_16x16x32_bf16(qf[ks], kf, sf[g][ks & 1], 0, 0, 0);
            }
        }
        __builtin_amdgcn_s_setprio(0);
        // ---- softmax (static-max; scalar bias is shift-invariant no-op) ----
        #pragma unroll
        for (int r = 0; r < 4; ++r) {
            float acc = 0.f;
            #pragma unroll
            for (int g = 0; g < 4; ++g) {
                bool va = (key0 + g * 16 + lr) < n;
                float pv = va ? exp2f(fmaf(sf[g][0][r] + sf[g][1][r], SL2E, -8.f)) : 0.f;
                acc += pv;
                Ps[par][p][16 * s + lq * 4 + r][g * 16 + lr] = f2bf(pv);
            }
            l_i[r] += acc;
        }
        // ---- single barrier per iteration: Ps[par] writes -> reads.
        // WAR on Ps[par] (rewrite at kt+2) is protected by the barrier at
        // kt+1 (all waves' PV(kt) reads precede their softmax(kt+1)).
        lds_barrier();
        bf16x8 pA[4];
        #pragma unroll
        for (int g = 0; g < 4; ++g)
            pA[g] = *(const bf16x8*)&Ps[par][p][l32][g * 16 + lh * 8];
        // ---- PV: B-frags streamed from L2 (frag-tiled Vt). ----
        __builtin_amdgcn_s_setprio(1);
        #pragma unroll
        for (int dt = 0; dt < 8; ++dt) {
            const int db = s * 8 + dt;
            #pragma unroll
            for (int g = 0; g < 4; ++g) {
                const int kt32 = (key0 >> 5) + (g >> 1);
                const ushort* a = Vseg + (size_t)kt32 * 16384 + db * 1024
                                + (g & 1) * 512 + l32 * 16 + lh * 8;
                bf16x8 v = *(const bf16x8*)a;
                o[dt] = __builtin_amdgcn_mfma_f32_32x32x16_bf16(pA[g], v, o[dt], 0, 0, 0);
            }
        }
        __builtin_amdgcn_s_setprio(0);
    }
    #pragma unroll
    for (int r = 0; r < 4; ++r)
        #pragma unroll
        for (int off = 1; off < 16; off <<= 1)
            l_i[r] += __shfl_xor(l_i[r], off, 16);
    const size_t growbase = (size_t)half * 16384 + (size_t)b * S + qt * 64;
    if (lr == 0) {
        #pragma unroll
        for (int r = 0; r < 4; ++r)
            Mlg[growbase + wave * 16 + lq * 4 + r] = l_i[r];
    }
    ushort* Pop = Pog + (growbase + p * 32) * 512;
    #pragma unroll
    for (int dt = 0; dt < 8; ++dt) {
        int ocol = s * 256 + dt * 32 + l32;
        #pragma unroll
        for (int r = 0; r < 16; ++r) {
            int orow = (r & 3) + 8 * (r >> 2) + 4 * lh;
            Pop[(size_t)orow * 512 + ocol] = f2bf(o[dt][r]);
        }
    }
}

// ---------------- combine the two key-halves ----------------
__global__ __launch_bounds__(256)
void combine_kernel(const ushort* __restrict__ Po, const float* __restrict__ Ml,
                    float* __restrict__ out)
{
    int i = (blockIdx.x * 256 + threadIdx.x) * 4;
    int row = i >> 9;
    float l = Ml[row] + Ml[16384 + row];
    float s = l > 0.f ? 1.f / l : 0.f;
    ushort4 p1 = *(const ushort4*)(Po + i);
    ushort4 p2 = *(const ushort4*)(Po + 8388608 + i);
    float4 o;
    o.x = (bf2f(p1.x) + bf2f(p2.x)) * s;
    o.y = (bf2f(p1.y) + bf2f(p2.y)) * s;
    o.z = (bf2f(p1.z) + bf2f(p2.z)) * s;
    o.w = (bf2f(p1.w) + bf2f(p2.w)) * s;
    *(float4*)(out + i) = o;
}

extern "C" void kernel_launch(void* const* d_in, const int* in_sizes, int n_in,
                              void* d_out, int out_size, void* d_ws, size_t ws_size,
                              hipStream_t stream) {
    const float* x  = (const float*)d_in[0];
    // d_in[1] = bias: additive scalar on all logits -> softmax shift-invariant -> no-op
    const int* mask = (const int*)d_in[2];
    const float* Wq = (const float*)d_in[3];
    const float* Wk = (const float*)d_in[4];
    const float* Wv = (const float*)d_in[5];
    float* out = (float*)d_out;

    // Workspace (ushort units) — layout unchanged; Kc/Vtc regions now hold the
    // fragment-tiled layouts (identical sizes: 16 segs x 524288 elements).
    ushort* ws   = (ushort*)d_ws;
    ushort* xb   = ws;
    ushort* wqT  = ws + 8388608;
    ushort* wkT  = wqT + 262144;
    ushort* wvb  = wkT + 262144;
    ushort* xc   = ws + 9175040;
    ushort* Pob  = ws + 9175040;
    ushort* Mb   = ws + 17563648;
    int*    idxb = (int*)(ws + 17825792);
    ushort* Kc   = ws + 25952256;
    ushort* Vtc  = ws + 34340864;
    float*  Mlb  = (float*)(ws + 42729472);
    int*    cntb = (int*)(ws + 42795008);

    prep_kernel<<<8592, 256, 0, stream>>>(x, Wq, Wk, Wv, mask,
                                          xb, wqT, wkT, wvb, idxb, cntb);
    gather_cvt<<<dim3(16, 16), 256, 0, stream>>>(xb, idxb, cntb, xc);
    // M = Wq^T Wk
    gemm_m<<<dim3(4, 4), 256, 0, stream>>>(wqT, wkT, Mb);
    // K'(frag-tiled) = xc M^T  and  Vt(frag-tiled) = Wv xc^T  (pad-band skip)
    gemm_kv<<<dim3(4, 128, 2), 256, 0, stream>>>(xc, Mb, Kc, wvb, Vtc, cntb);
    attn_kernel<<<dim3(32, 8, 2), 256, 0, stream>>>(xb, Kc, Vtc, cntb, Pob, Mlb);
    combine_kernel<<<8192, 256, 0, stream>>>(Pob, Mlb, out);
}

// Round 7
// 214.217 us; speedup vs baseline: 1.8693x; 1.8693x over previous
//
#include <hip/hip_runtime.h>

typedef short bf16x8 __attribute__((ext_vector_type(8)));
typedef float f32x4 __attribute__((ext_vector_type(4)));
typedef float f32x16 __attribute__((ext_vector_type(16)));

__device__ __forceinline__ ushort f2bf(float f) {
    union { float f; unsigned u; } v; v.f = f;
    unsigned r = (v.u + 0x7fffu + ((v.u >> 16) & 1u)) >> 16;
    return (ushort)r;
}
__device__ __forceinline__ float bf2f(ushort u) {
    union { unsigned u; float f; } v; v.u = ((unsigned)u) << 16;
    return v.f;
}
__device__ __forceinline__ void async_copy16(void* lds, const void* g) {
    __builtin_amdgcn_global_load_lds(
        (const __attribute__((address_space(1))) unsigned*)g,
        (__attribute__((address_space(3))) unsigned*)lds, 16, 0, 0);
}
// Barrier that waits only LDS ops — leaves global/vmcnt prefetches in flight.
__device__ __forceinline__ void lds_barrier() {
    asm volatile("s_waitcnt lgkmcnt(0)\n\ts_barrier" ::: "memory");
}

// ---------------- fused prep: cvt_x | cvt_wT(Wq,Wk) | cvt(Wv) | compact ------
__global__ __launch_bounds__(256)
void prep_kernel(const float* __restrict__ x, const float* __restrict__ Wq,
                 const float* __restrict__ Wk, const float* __restrict__ Wv,
                 const int* __restrict__ mask,
                 ushort* __restrict__ xb, ushort* __restrict__ wqT,
                 ushort* __restrict__ wkT, ushort* __restrict__ wvb,
                 int* __restrict__ idx, int* __restrict__ cnt)
{
    const int bid = blockIdx.x, t = threadIdx.x;
    if (bid < 8192) {                       // x fp32 -> bf16
        int i = (bid * 256 + t) * 4;
        float4 v = *(const float4*)(x + i);
        ushort4 o;
        o.x = f2bf(v.x); o.y = f2bf(v.y); o.z = f2bf(v.z); o.w = f2bf(v.w);
        *(ushort4*)(xb + i) = o;
    } else if (bid < 8320) {                // Wq/Wk transpose-convert
        __shared__ ushort T[64][72];
        int r = bid - 8192;
        const int z = r >> 6; r &= 63;
        const float* in = z ? Wk : Wq;
        ushort* out     = z ? wkT : wqT;
        const int r0 = (r >> 3) * 64, c0 = (r & 7) * 64;
        const int rr = t >> 3, cc8 = (t & 7) * 8;
        #pragma unroll
        for (int pass = 0; pass < 2; ++pass) {
            int rw = rr + pass * 32;
            float4 a = *(const float4*)(in + (size_t)(r0 + rw) * 512 + c0 + cc8);
            float4 bq = *(const float4*)(in + (size_t)(r0 + rw) * 512 + c0 + cc8 + 4);
            T[rw][cc8+0]=f2bf(a.x);  T[rw][cc8+1]=f2bf(a.y);  T[rw][cc8+2]=f2bf(a.z);  T[rw][cc8+3]=f2bf(a.w);
            T[rw][cc8+4]=f2bf(bq.x); T[rw][cc8+5]=f2bf(bq.y); T[rw][cc8+6]=f2bf(bq.z); T[rw][cc8+7]=f2bf(bq.w);
        }
        __syncthreads();
        const int c = t >> 2, seg = (t & 3) * 16;
        ushort tmp[16];
        #pragma unroll
        for (int j = 0; j < 16; ++j) tmp[j] = T[seg + j][c];
        *(uint4*)(out + (size_t)(c0 + c) * 512 + r0 + seg)     = *(uint4*)&tmp[0];
        *(uint4*)(out + (size_t)(c0 + c) * 512 + r0 + seg + 8) = *(uint4*)&tmp[8];
    } else if (bid < 8576) {                // Wv fp32 -> bf16
        int i = ((bid - 8320) * 256 + t) * 4;
        float4 v = *(const float4*)(Wv + i);
        ushort4 o;
        o.x = f2bf(v.x); o.y = f2bf(v.y); o.z = f2bf(v.z); o.w = f2bf(v.w);
        *(ushort4*)(wvb + i) = o;
    } else {                                // mask compaction
        __shared__ int sc[256];
        int seg = bid - 8576, b = seg >> 1, half = seg & 1;
        const int* m = mask + b * 2048 + half * 1024;
        int v0 = (m[t*4+0] == 0), v1 = (m[t*4+1] == 0);
        int v2 = (m[t*4+2] == 0), v3 = (m[t*4+3] == 0);
        int c = v0 + v1 + v2 + v3;
        sc[t] = c; __syncthreads();
        for (int ofs = 1; ofs < 256; ofs <<= 1) {
            int xx = (t >= ofs) ? sc[t - ofs] : 0;
            __syncthreads(); sc[t] += xx; __syncthreads();
        }
        int pos = sc[t] - c + seg * 1024;
        if (v0) idx[pos++] = t*4+0;
        if (v1) idx[pos++] = t*4+1;
        if (v2) idx[pos++] = t*4+2;
        if (v3) idx[pos++] = t*4+3;
        if (t == 255) cnt[seg] = sc[255];
    }
}

// --------- row translation: compacted key-row -> absolute xb row -------------
// row in [0,16384): seg = row>>10, j = row&1023. j < cnt[seg] -> idx'd source
// row; else clamp to the segment's row 0 (finite garbage; never contributes:
// K' rows >= n are va-masked in attn, V cols >= n multiply p=0).
__device__ __forceinline__ int map_row(const int* __restrict__ idx,
                                       const int* __restrict__ cnt, int row) {
    int seg = row >> 10, j = row & 1023;
    int src = (j < cnt[seg]) ? idx[(seg << 10) + j] : 0;
    return (seg << 10) + src;
}

// ---------------- shared GEMM core: C[m][n] = sum_k A[m][k]*B[n][k] ----------
// mapA/mapB (compile-time 0/1): translate operand rows through idx/cnt
// (on-the-fly gather from xb — replaces the gather_cvt pass).
__device__ __forceinline__ void gemm_core(const ushort* __restrict__ A,
                                          const ushort* __restrict__ B,
                                          ushort* __restrict__ C,
                                          int N, int K, int mBase, int nBase,
                                          int mapA, int mapB,
                                          const int* __restrict__ idx,
                                          const int* __restrict__ cnt)
{
    __shared__ ushort As[128][32];
    __shared__ ushort Bs[128][32];
    const int tid = threadIdx.x;
    const int lane = tid & 63, wave = tid >> 6;
    const int wm = wave >> 1, wn = wave & 1;
    const int lr = lane & 15, lq = lane >> 4;
    const int sr = lane >> 2;
    const int sc = (lane & 3) * 8;

    // Per-thread staging source pointers (fixed across the K loop).
    const ushort* aptr[2];
    const ushort* bptr[2];
    #pragma unroll
    for (int j = 0; j < 2; ++j) {
        int ra = mBase + wave * 32 + j * 16 + sr;
        int rb = nBase + wave * 32 + j * 16 + sr;
        int sa = mapA ? map_row(idx, cnt, ra) : ra;
        int sb = mapB ? map_row(idx, cnt, rb) : rb;
        aptr[j] = A + (size_t)sa * K + sc;
        bptr[j] = B + (size_t)sb * K + sc;
    }

    f32x4 acc[4][4];
    #pragma unroll
    for (int i = 0; i < 4; ++i)
        #pragma unroll
        for (int j = 0; j < 4; ++j) acc[i][j] = (f32x4){0.f, 0.f, 0.f, 0.f};

    for (int k0 = 0; k0 < K; k0 += 32) {
        __syncthreads();
        #pragma unroll
        for (int j = 0; j < 2; ++j) {
            int rbase = wave * 32 + j * 16;
            async_copy16(&As[rbase][0], aptr[j] + k0);
            async_copy16(&Bs[rbase][0], bptr[j] + k0);
        }
        __syncthreads();
        bf16x8 af[4], bfr[4];
        #pragma unroll
        for (int mi = 0; mi < 4; ++mi) af[mi] = *(const bf16x8*)&As[wm * 64 + mi * 16 + lr][lq * 8];
        #pragma unroll
        for (int ni = 0; ni < 4; ++ni) bfr[ni] = *(const bf16x8*)&Bs[wn * 64 + ni * 16 + lr][lq * 8];
        #pragma unroll
        for (int mi = 0; mi < 4; ++mi)
            #pragma unroll
            for (int ni = 0; ni < 4; ++ni)
                acc[mi][ni] = __builtin_amdgcn_mfma_f32_16x16x32_bf16(af[mi], bfr[ni], acc[mi][ni], 0, 0, 0);
    }
    #pragma unroll
    for (int mi = 0; mi < 4; ++mi)
        #pragma unroll
        for (int ni = 0; ni < 4; ++ni)
            #pragma unroll
            for (int r = 0; r < 4; ++r) {
                int m = mBase + wm * 64 + mi * 16 + lq * 4 + r;
                int n = nBase + wn * 64 + ni * 16 + lr;
                C[(size_t)m * N + n] = f2bf(acc[mi][ni][r]);
            }
}

__global__ __launch_bounds__(256, 2)
void gemm_m(const ushort* __restrict__ A, const ushort* __restrict__ B,
            ushort* __restrict__ C) {
    gemm_core(A, B, C, 512, 512, blockIdx.y * 128, blockIdx.x * 128,
              0, 0, nullptr, nullptr);
}

// fused K' and Vt gemms (z-decode); both skip all-pad 128-bands and gather
// compacted rows from xb via idx on the fly (no separate gather pass).
__global__ __launch_bounds__(256, 2)
void gemm_kv(const ushort* __restrict__ xb, const ushort* __restrict__ Mb,
             ushort* __restrict__ Kc, const ushort* __restrict__ wv,
             ushort* __restrict__ Vtc, const int* __restrict__ idx,
             const int* __restrict__ cnt)
{
    if (blockIdx.z == 0) {
        int mBase = blockIdx.y * 128, nBase = blockIdx.x * 128;
        if ((mBase & 1023) >= cnt[mBase >> 10]) return;
        gemm_core(xb, Mb, Kc, 512, 512, mBase, nBase, 1, 0, idx, cnt);
    } else {
        int mBase = blockIdx.x * 128, nBase = blockIdx.y * 128;
        if ((nBase & 1023) >= cnt[nBase >> 10]) return;
        gemm_core(wv, xb, Vtc, 16384, 512, mBase, nBase, 0, 1, idx, cnt);
    }
}

// ---------------- flash attention over COMPACTED keys (R3-exact) -------------
// Q = xb [B*S][512] bf16. K'c: [16][1024][512]. Vtc: [512][16*1024].
// Grid (32,8,2). 32-key tiles, pair-split PV (mfma 32x32x16), static-max.
// K staged via global_load_lds issued after the mid lgkm-barrier (hides under
// PV, drained one phase later at the top __syncthreads). V reg-staged. XCD
// swizzle + 4-chain QK + setprio. Known-good 88 us (R3).
__global__ __launch_bounds__(256, 2)
void attn_kernel(const ushort* __restrict__ Qg, const ushort* __restrict__ Kcg,
                 const ushort* __restrict__ Vtcg, const int* __restrict__ cntg,
                 ushort* __restrict__ Pog, float* __restrict__ Mlg)
{
    const int S = 2048;
    const float SL2E = 0.0637587160f;  // (1/sqrt(512)) * log2(e)

    __shared__ ushort Ks[32][548];
    __shared__ ushort Vs[512][36];
    __shared__ ushort Ps[2][32][36];

    // XCD swizzle: all 32 q-tiles of a segment on one XCD (2 segs/XCD).
    const int lin = blockIdx.x + 32 * blockIdx.y + 256 * blockIdx.z;
    const int seg = (lin & 7) * 2 + (lin >> 8);
    const int qt  = (lin >> 3) & 31;
    const int b = seg >> 1, half = seg & 1;

    const int tid = threadIdx.x, lane = tid & 63, wave = tid >> 6;
    const int lr = lane & 15, lq = lane >> 4;
    const int p = wave >> 1, s = wave & 1;
    const int l32 = lane & 31, lh = lane >> 5;

    const int n = cntg[seg];
    const int ntiles = (n + 31) >> 5;

    const ushort* Qp = Qg + ((size_t)b * S + qt * 64 + wave * 16 + lr) * 512;
    bf16x8 qf[16];
    #pragma unroll
    for (int c = 0; c < 16; ++c) qf[c] = *(const bf16x8*)(Qp + c * 32 + lq * 8);

    f32x16 o[8];
    #pragma unroll
    for (int i = 0; i < 8; ++i)
        #pragma unroll
        for (int r = 0; r < 16; ++r) o[i][r] = 0.f;
    float l_i[4] = {0.f, 0.f, 0.f, 0.f};

    const char* Kseg = (const char*)(Kcg + (size_t)seg * 1024 * 512);
    const char* Vseg = (const char*)Vtcg + (size_t)(seg * 1024) * 2;

    // Prologue: issue K(0) -> Ks (async, 8 rows per wave).
    {
        #pragma unroll
        for (int i = 0; i < 8; ++i) {
            int row = wave * 8 + i;
            async_copy16(&Ks[row][0], Kseg + (size_t)row * 1024 + lane * 16);
        }
    }

    for (int kt = 0; kt < ntiles; ++kt) {
        const int key0 = kt * 32;
        // Top barrier: drains vmcnt(0) -> Ks(kt) landed (issued one full
        // PV-phase ago, except iter 0); Vs/Ps free.
        __syncthreads();
        // V tile kt -> regs; in flight across the QK phase.
        uint4 vreg[8];
        {
            const char* gV = Vseg + (size_t)key0 * 2;
            #pragma unroll
            for (int i = 0; i < 8; ++i) {
                int off = i * 4096 + tid * 16;
                vreg[i] = *(const uint4*)(gV + (size_t)(off >> 6) * 32768 + (off & 63));
            }
        }
        const bool va0 = (key0 + lr) < n;
        const bool va1 = (key0 + 16 + lr) < n;
        // QK^T: 4 independent accumulator chains for MFMA-latency slack.
        f32x4 sA = (f32x4){0.f,0.f,0.f,0.f}, sB = (f32x4){0.f,0.f,0.f,0.f};
        f32x4 sC = (f32x4){0.f,0.f,0.f,0.f}, sD = (f32x4){0.f,0.f,0.f,0.f};
        __builtin_amdgcn_s_setprio(1);
        #pragma unroll
        for (int ks = 0; ks < 16; ks += 2) {
            bf16x8 kf0a = *(const bf16x8*)&Ks[lr][ks * 32 + lq * 8];
            bf16x8 kf1a = *(const bf16x8*)&Ks[16 + lr][ks * 32 + lq * 8];
            bf16x8 kf0b = *(const bf16x8*)&Ks[lr][(ks + 1) * 32 + lq * 8];
            bf16x8 kf1b = *(const bf16x8*)&Ks[16 + lr][(ks + 1) * 32 + lq * 8];
            sA = __builtin_amdgcn_mfma_f32_16x16x32_bf16(qf[ks], kf0a, sA, 0, 0, 0);
            sB = __builtin_amdgcn_mfma_f32_16x16x32_bf16(qf[ks], kf1a, sB, 0, 0, 0);
            sC = __builtin_amdgcn_mfma_f32_16x16x32_bf16(qf[ks + 1], kf0b, sC, 0, 0, 0);
            sD = __builtin_amdgcn_mfma_f32_16x16x32_bf16(qf[ks + 1], kf1b, sD, 0, 0, 0);
        }
        __builtin_amdgcn_s_setprio(0);
        #pragma unroll
        for (int r = 0; r < 4; ++r) {
            float s0 = sA[r] + sC[r], s1 = sB[r] + sD[r];
            float p0 = va0 ? exp2f(fmaf(s0, SL2E, -8.f)) : 0.f;
            float p1 = va1 ? exp2f(fmaf(s1, SL2E, -8.f)) : 0.f;
            l_i[r] += p0 + p1;
            Ps[p][16 * s + lq * 4 + r][lr]      = f2bf(p0);
            Ps[p][16 * s + lq * 4 + r][16 + lr] = f2bf(p1);
        }
        // Commit V tile to LDS (compiler waits vmcnt for vreg only — the K
        // prefetch for kt+1 has not been issued yet, so no false drain).
        #pragma unroll
        for (int i = 0; i < 8; ++i) {
            int off = i * 4096 + tid * 16;
            int row = off >> 6, col = off & 63;
            *(uint4*)((char*)Vs + row * 72 + col) = vreg[i];
        }
        // Mid barrier (lgkm only): Ps + Vs visible; all waves are past their
        // QK reads of Ks -> Ks is dead, safe to overwrite asynchronously.
        lds_barrier();
        // Issue K(kt+1) now; its latency hides under the PV phase below and
        // is drained by the NEXT top __syncthreads().
        if (kt + 1 < ntiles) {
            const char* gK = Kseg + (size_t)(key0 + 32) * 1024;
            #pragma unroll
            for (int i = 0; i < 8; ++i) {
                int row = wave * 8 + i;
                async_copy16(&Ks[row][0], gK + (size_t)row * 1024 + lane * 16);
            }
        }
        bf16x8 pA0 = *(const bf16x8*)&Ps[p][l32][lh * 8];
        bf16x8 pA1 = *(const bf16x8*)&Ps[p][l32][16 + lh * 8];
        __builtin_amdgcn_s_setprio(1);
        #pragma unroll
        for (int dt = 0; dt < 8; ++dt) {
            int d = s * 256 + dt * 32 + l32;
            bf16x8 v0 = *(const bf16x8*)&Vs[d][lh * 8];
            bf16x8 v1 = *(const bf16x8*)&Vs[d][16 + lh * 8];
            o[dt] = __builtin_amdgcn_mfma_f32_32x32x16_bf16(pA0, v0, o[dt], 0, 0, 0);
            o[dt] = __builtin_amdgcn_mfma_f32_32x32x16_bf16(pA1, v1, o[dt], 0, 0, 0);
        }
        __builtin_amdgcn_s_setprio(0);
    }
    #pragma unroll
    for (int r = 0; r < 4; ++r)
        #pragma unroll
        for (int off = 1; off < 16; off <<= 1)
            l_i[r] += __shfl_xor(l_i[r], off, 16);
    const size_t growbase = (size_t)half * 16384 + (size_t)b * S + qt * 64;
    if (lr == 0) {
        #pragma unroll
        for (int r = 0; r < 4; ++r)
            Mlg[growbase + wave * 16 + lq * 4 + r] = l_i[r];
    }
    ushort* Pop = Pog + (growbase + p * 32) * 512;
    #pragma unroll
    for (int dt = 0; dt < 8; ++dt) {
        int ocol = s * 256 + dt * 32 + l32;
        #pragma unroll
        for (int r = 0; r < 16; ++r) {
            int orow = (r & 3) + 8 * (r >> 2) + 4 * lh;
            Pop[(size_t)orow * 512 + ocol] = f2bf(o[dt][r]);
        }
    }
}

// ---------------- combine the two key-halves ----------------
__global__ __launch_bounds__(256)
void combine_kernel(const ushort* __restrict__ Po, const float* __restrict__ Ml,
                    float* __restrict__ out)
{
    int i = (blockIdx.x * 256 + threadIdx.x) * 4;
    int row = i >> 9;
    float l = Ml[row] + Ml[16384 + row];
    float s = l > 0.f ? 1.f / l : 0.f;
    ushort4 p1 = *(const ushort4*)(Po + i);
    ushort4 p2 = *(const ushort4*)(Po + 8388608 + i);
    float4 o;
    o.x = (bf2f(p1.x) + bf2f(p2.x)) * s;
    o.y = (bf2f(p1.y) + bf2f(p2.y)) * s;
    o.z = (bf2f(p1.z) + bf2f(p2.z)) * s;
    o.w = (bf2f(p1.w) + bf2f(p2.w)) * s;
    *(float4*)(out + i) = o;
}

extern "C" void kernel_launch(void* const* d_in, const int* in_sizes, int n_in,
                              void* d_out, int out_size, void* d_ws, size_t ws_size,
                              hipStream_t stream) {
    const float* x  = (const float*)d_in[0];
    // d_in[1] = bias: additive scalar on all logits -> softmax shift-invariant -> no-op
    const int* mask = (const int*)d_in[2];
    const float* Wq = (const float*)d_in[3];
    const float* Wk = (const float*)d_in[4];
    const float* Wv = (const float*)d_in[5];
    float* out = (float*)d_out;

    // Workspace (ushort units). xc region now unused (gather fused into gemm).
    ushort* ws   = (ushort*)d_ws;
    ushort* xb   = ws;
    ushort* wqT  = ws + 8388608;
    ushort* wkT  = wqT + 262144;
    ushort* wvb  = wkT + 262144;
    ushort* Pob  = ws + 9175040;
    ushort* Mb   = ws + 17563648;
    int*    idxb = (int*)(ws + 17825792);
    ushort* Kc   = ws + 25952256;
    ushort* Vtc  = ws + 34340864;
    float*  Mlb  = (float*)(ws + 42729472);
    int*    cntb = (int*)(ws + 42795008);

    prep_kernel<<<8592, 256, 0, stream>>>(x, Wq, Wk, Wv, mask,
                                          xb, wqT, wkT, wvb, idxb, cntb);
    // M = Wq^T Wk
    gemm_m<<<dim3(4, 4), 256, 0, stream>>>(wqT, wkT, Mb);
    // K'c = gather(xb) M^T  and  Vtc = Wv gather(xb)^T  (fused gather + skip)
    gemm_kv<<<dim3(4, 128, 2), 256, 0, stream>>>(xb, Mb, Kc, wvb, Vtc, idxb, cntb);
    attn_kernel<<<dim3(32, 8, 2), 256, 0, stream>>>(xb, Kc, Vtc, cntb, Pob, Mlb);
    combine_kernel<<<8192, 256, 0, stream>>>(Pob, Mlb, out);
}